// Round 12
// baseline (1038.375 us; speedup 1.0000x reference)
//
#include <hip/hip_runtime.h>
#include <hip/hip_fp16.h>

#define EMB_D 64
#define SB 1024   // scan block size
#define CCH 32    // chunks (deterministic counting sort)
#define NPB 32    // nodes per coarse bucket (bucket = v>>5, localv = v&31)

// ===========================================================================
// Tier A (new): atomic-free chunked counting sort + LDS-accumulate gather.
//   P1: per-chunk LDS hist over coarse buckets (+ fused fp16 cast)
//   scan: 3-phase over counts[b][c]  ->  offsets[b][c]
//   P3: LDS-cursor scatter to exact slots (packed src|w + localv), no atomics
//   P4: one block per bucket, LDS fp32 acc[32][64], fused L2 norm
// Tier B: R11 pipeline (proven 308 us). Tier C: atomic scatter.
// ===========================================================================

__device__ __forceinline__ float h15_to_float(unsigned int bits) {
    return __half2float(__ushort_as_half((unsigned short)bits));
}

// --- P1: fused cast + per-chunk bucket histogram (LDS) --------------------
__global__ void p1_cast_hist(const float2* __restrict__ embin,
                             __half2* __restrict__ emb16, int n2,
                             const int* __restrict__ dst,
                             int* __restrict__ counts,   // [B][CCH]
                             int E, int ppc, int B) {
    extern __shared__ int hcnt[];   // B ints
    if (blockIdx.x >= CCH) {
        int i = (blockIdx.x - CCH) * blockDim.x + threadIdx.x;
        int st = (gridDim.x - CCH) * blockDim.x;
        for (; i < n2; i += st)
            emb16[i] = __float22half2_rn(embin[i]);
        return;
    }
    const int c = blockIdx.x;
    for (int j = threadIdx.x; j < B; j += blockDim.x) hcnt[j] = 0;
    __syncthreads();
    int lo = c * ppc, hi = min(lo + ppc, E);
    for (int i = lo + threadIdx.x; i < hi; i += blockDim.x)
        atomicAdd(&hcnt[dst[i] >> 5], 1);
    __syncthreads();
    for (int j = threadIdx.x; j < B; j += blockDim.x)
        counts[j * CCH + c] = hcnt[j];
}

// --- generic 3-phase exclusive scan over M entries ------------------------
__global__ void scan_reduceB(const int* __restrict__ counts,
                             int* __restrict__ partial, int M) {
    __shared__ int wsum[16];
    const int tid = threadIdx.x, lane = tid & 63, wid = tid >> 6;
    int i = blockIdx.x * SB + tid;
    int v = (i < M) ? counts[i] : 0;
    #pragma unroll
    for (int off = 32; off > 0; off >>= 1)
        v += __shfl_xor(v, off, 64);
    if (lane == 0) wsum[wid] = v;
    __syncthreads();
    if (tid == 0) {
        int s = 0;
        #pragma unroll
        for (int k = 0; k < 16; ++k) s += wsum[k];
        partial[blockIdx.x] = s;
    }
}

__global__ void scan_partials(const int* __restrict__ partial,
                              int* __restrict__ blockoff,
                              int* __restrict__ offsets, int numB, int M) {
    __shared__ int wsum[16];
    __shared__ int wpre[16];
    const int tid = threadIdx.x, lane = tid & 63, wid = tid >> 6;
    int v = (tid < numB) ? partial[tid] : 0;
    int x = v;
    #pragma unroll
    for (int off = 1; off < 64; off <<= 1) {
        int t = __shfl_up(x, off, 64);
        if (lane >= off) x += t;
    }
    if (lane == 63) wsum[wid] = x;
    __syncthreads();
    if (wid == 0) {
        int s = (lane < 16) ? wsum[lane] : 0;
        #pragma unroll
        for (int off = 1; off < 16; off <<= 1) {
            int t = __shfl_up(s, off, 64);
            if (lane >= off) s += t;
        }
        if (lane < 16) wpre[lane] = s;
    }
    __syncthreads();
    int excl = ((wid > 0) ? wpre[wid - 1] : 0) + (x - v);
    if (tid < numB) blockoff[tid] = excl;
    if (tid == 0) offsets[M] = wpre[15];   // grand total = E
}

__global__ void scan_applyB(const int* __restrict__ counts,
                            const int* __restrict__ blockoff,
                            int* __restrict__ offsets, int M) {
    __shared__ int wsum[16];
    __shared__ int wpre[16];
    const int tid = threadIdx.x, lane = tid & 63, wid = tid >> 6;
    int i = blockIdx.x * SB + tid;
    int v = (i < M) ? counts[i] : 0;
    int x = v;
    #pragma unroll
    for (int off = 1; off < 64; off <<= 1) {
        int t = __shfl_up(x, off, 64);
        if (lane >= off) x += t;
    }
    if (lane == 63) wsum[wid] = x;
    __syncthreads();
    if (wid == 0) {
        int s = (lane < 16) ? wsum[lane] : 0;
        #pragma unroll
        for (int off = 1; off < 16; off <<= 1) {
            int t = __shfl_up(s, off, 64);
            if (lane >= off) s += t;
        }
        if (lane < 16) wpre[lane] = s;
    }
    __syncthreads();
    int excl = blockoff[blockIdx.x] + ((wid > 0) ? wpre[wid - 1] : 0) + (x - v);
    if (i < M) offsets[i] = excl;
}

// --- P3: deterministic scatter, LDS cursors, zero global atomics ----------
__global__ void p3_scatter(const int* __restrict__ src,
                           const int* __restrict__ dst,
                           const float* __restrict__ w,
                           const int* __restrict__ offsets,  // [B][CCH]
                           unsigned int* __restrict__ eb4,
                           unsigned char* __restrict__ lv8,
                           int E, int ppc, int B) {
    extern __shared__ int cur[];    // B ints
    const int c = blockIdx.x;
    for (int j = threadIdx.x; j < B; j += blockDim.x)
        cur[j] = offsets[j * CCH + c];
    __syncthreads();
    int lo = c * ppc, hi = min(lo + ppc, E);
    for (int i = lo + threadIdx.x; i < hi; i += blockDim.x) {
        int v = dst[i];
        int b = v >> 5;
        int slot = atomicAdd(&cur[b], 1);   // LDS atomic
        unsigned int wb = __half_as_ushort(__float2half_rn(w[i]));
        eb4[slot] = ((unsigned int)src[i] << 15) | (wb & 0x7FFFu);
        lv8[slot] = (unsigned char)(v & 31);
    }
}

// --- P4: per-bucket LDS accumulation + fused L2 normalize -----------------
// Quarter q = lane>>4 handles edge idx; lane ql = lane&15 owns dims
// [4ql,4ql+4) via one 8B uint2 row read. Edges in any order (LDS f32 atomics).
__global__ __launch_bounds__(256) void p4_gather(
        const uint2* __restrict__ emb16,      // row v = 16 x uint2 (128 B)
        const int* __restrict__ offsets,      // [B][CCH] (+[M]=E)
        const unsigned int* __restrict__ eb4,
        const unsigned char* __restrict__ lv8,
        float* __restrict__ out, int N) {
    __shared__ float acc[NPB][EMB_D];         // 8 KB
    const int b = blockIdx.x;
    const int tid = threadIdx.x;
    const int wid = tid >> 6, lane = tid & 63;
    const int q = lane >> 4, ql = lane & 15;

    for (int j = tid; j < NPB * EMB_D; j += blockDim.x)
        ((float*)acc)[j] = 0.0f;
    __syncthreads();

    int beg = offsets[b * CCH];
    int end = offsets[(b + 1) * CCH];   // offsets[M] = E covers last bucket

    for (int idx = beg + wid * 4 + q; idx < end; idx += 16) {
        unsigned int pk = eb4[idx];
        int lv = lv8[idx];
        float wt = h15_to_float(pk & 0x7FFFu);
        uint2 r = emb16[(size_t)(pk >> 15) * 16 + ql];
        float2 x01 = __half22float2(*reinterpret_cast<__half2*>(&r.x));
        float2 x23 = __half22float2(*reinterpret_cast<__half2*>(&r.y));
        atomicAdd(&acc[lv][(ql << 2) + 0], x01.x * wt);
        atomicAdd(&acc[lv][(ql << 2) + 1], x01.y * wt);
        atomicAdd(&acc[lv][(ql << 2) + 2], x23.x * wt);
        atomicAdd(&acc[lv][(ql << 2) + 3], x23.y * wt);
    }
    __syncthreads();

    // normalize: 4 waves x 8 nodes; lane = dim
    #pragma unroll
    for (int k = 0; k < 8; ++k) {
        int n = wid * 8 + k;
        int v = (b << 5) + n;
        if (v < N) {
            float x = acc[n][lane];
            float ss = x * x;
            #pragma unroll
            for (int off = 32; off > 0; off >>= 1)
                ss += __shfl_xor(ss, off, 64);
            float scale = 1.0f / fmaxf(sqrtf(ss), 1e-12f);
            out[(size_t)v * EMB_D + lane] = x * scale;
        }
    }
}

// ===========================================================================
// Tier B: R11 pipeline (proven 308 us) — 8-way hist, cursor-atomic bucket.
// ===========================================================================
#define CAST_BLOCKS 256
__global__ void fused_cast_hist(const float2* __restrict__ embin,
                                __half2* __restrict__ emb16, int n2,
                                const int* __restrict__ dst,
                                int* __restrict__ counts8, int E, int N) {
    if (blockIdx.x < CAST_BLOCKS) {
        int i = blockIdx.x * blockDim.x + threadIdx.x;
        int st = CAST_BLOCKS * blockDim.x;
        for (; i < n2; i += st)
            emb16[i] = __float22half2_rn(embin[i]);
    } else {
        int* mycounts = counts8 + (size_t)(blockIdx.x & 7) * N;
        int i = (blockIdx.x - CAST_BLOCKS) * blockDim.x + threadIdx.x;
        int st = (gridDim.x - CAST_BLOCKS) * blockDim.x;
        for (; i < E; i += st)
            atomicAdd(&mycounts[dst[i]], 1);
    }
}

__device__ __forceinline__ int fold_counts(const int* counts8, int i, int N) {
    int v = 0;
    #pragma unroll
    for (int g = 0; g < 8; ++g) v += counts8[(size_t)g * N + i];
    return v;
}

__global__ void scan_reduceF(const int* __restrict__ counts8,
                             int* __restrict__ partial, int N) {
    __shared__ int wsum[16];
    const int tid = threadIdx.x, lane = tid & 63, wid = tid >> 6;
    int i = blockIdx.x * SB + tid;
    int v = (i < N) ? fold_counts(counts8, i, N) : 0;
    #pragma unroll
    for (int off = 32; off > 0; off >>= 1)
        v += __shfl_xor(v, off, 64);
    if (lane == 0) wsum[wid] = v;
    __syncthreads();
    if (tid == 0) {
        int s = 0;
        #pragma unroll
        for (int k = 0; k < 16; ++k) s += wsum[k];
        partial[blockIdx.x] = s;
    }
}

__global__ void scan_applyF(const int* __restrict__ counts8,
                            const int* __restrict__ blockoff,
                            int* __restrict__ offsets,
                            int* __restrict__ cursors, int N) {
    __shared__ int wsum[16];
    __shared__ int wpre[16];
    const int tid = threadIdx.x, lane = tid & 63, wid = tid >> 6;
    int i = blockIdx.x * SB + tid;
    int v = (i < N) ? fold_counts(counts8, i, N) : 0;
    int x = v;
    #pragma unroll
    for (int off = 1; off < 64; off <<= 1) {
        int t = __shfl_up(x, off, 64);
        if (lane >= off) x += t;
    }
    if (lane == 63) wsum[wid] = x;
    __syncthreads();
    if (wid == 0) {
        int s = (lane < 16) ? wsum[lane] : 0;
        #pragma unroll
        for (int off = 1; off < 16; off <<= 1) {
            int t = __shfl_up(s, off, 64);
            if (lane >= off) s += t;
        }
        if (lane < 16) wpre[lane] = s;
    }
    __syncthreads();
    int excl = blockoff[blockIdx.x] + ((wid > 0) ? wpre[wid - 1] : 0) + (x - v);
    if (i < N) { offsets[i] = excl; cursors[i] = excl; }
}

__global__ void bucketS_kernel(const int* __restrict__ src,
                               const int* __restrict__ dst,
                               const float* __restrict__ w,
                               int* __restrict__ cursors,
                               unsigned int* __restrict__ packed,
                               int E, int span, int N) {
    int g = blockIdx.x & 7;
    int b = blockIdx.x >> 3;
    int lo = g * span;
    int hi = min(lo + span, N);
    int stride = (gridDim.x >> 3) * blockDim.x;
    for (int i = b * blockDim.x + threadIdx.x; i < E; i += stride) {
        int v = dst[i];
        if (v >= lo && v < hi) {
            int slot = atomicAdd(&cursors[v], 1);
            unsigned int wb = __half_as_ushort(__float2half_rn(w[i]));
            packed[slot] = ((unsigned int)src[i] << 15) | (wb & 0x7FFFu);
        }
    }
}

__global__ __launch_bounds__(256) void gatherS_kernel(
        const uint2* __restrict__ emb16,
        const int* __restrict__ offsets,
        const unsigned int* __restrict__ packed,
        float* __restrict__ out, int N) {
    int node = blockIdx.x * 4 + (threadIdx.x >> 6);
    int lane = threadIdx.x & 63;
    if (node >= N) return;
    int q  = lane >> 4;
    int ql = lane & 15;

    int beg = offsets[node];
    int end = offsets[node + 1];

    float a0 = 0.f, a1 = 0.f, a2 = 0.f, a3 = 0.f;

    int idx0 = beg + q;
    unsigned int pk0 = (idx0 < end) ? packed[idx0] : 0u;
    uint2 r0 = emb16[(size_t)(pk0 >> 15) * 16 + ql];

    for (int j = beg; j < end; j += 4) {
        int idx1 = idx0 + 4;
        unsigned int pk1 = (idx1 < end) ? packed[idx1] : 0u;
        uint2 r1 = emb16[(size_t)(pk1 >> 15) * 16 + ql];

        float wt = h15_to_float(pk0 & 0x7FFFu);
        float2 x01 = __half22float2(*reinterpret_cast<__half2*>(&r0.x));
        float2 x23 = __half22float2(*reinterpret_cast<__half2*>(&r0.y));
        a0 = fmaf(x01.x, wt, a0);
        a1 = fmaf(x01.y, wt, a1);
        a2 = fmaf(x23.x, wt, a2);
        a3 = fmaf(x23.y, wt, a3);

        pk0 = pk1; r0 = r1; idx0 = idx1;
    }

    a0 += __shfl_xor(a0, 16, 64); a0 += __shfl_xor(a0, 32, 64);
    a1 += __shfl_xor(a1, 16, 64); a1 += __shfl_xor(a1, 32, 64);
    a2 += __shfl_xor(a2, 16, 64); a2 += __shfl_xor(a2, 32, 64);
    a3 += __shfl_xor(a3, 16, 64); a3 += __shfl_xor(a3, 32, 64);

    float ss = a0 * a0 + a1 * a1 + a2 * a2 + a3 * a3;
    #pragma unroll
    for (int off = 8; off > 0; off >>= 1)
        ss += __shfl_xor(ss, off, 64);
    float scale = 1.0f / fmaxf(sqrtf(ss), 1e-12f);

    if (q == 0) {
        float4 o = make_float4(a0 * scale, a1 * scale, a2 * scale, a3 * scale);
        reinterpret_cast<float4*>(out + (size_t)node * EMB_D)[ql] = o;
    }
}

// ===========================================================================
// Tier C: atomic scatter fallback.
// ===========================================================================
__global__ void lightgcn_scatter(const float* __restrict__ emb,
                                 const float* __restrict__ w,
                                 const int* __restrict__ src,
                                 const int* __restrict__ dst,
                                 float* __restrict__ h, int E) {
    long long t = (long long)blockIdx.x * blockDim.x + threadIdx.x;
    int e = (int)(t >> 4);
    int d = (int)(t & 15) << 2;
    if (e >= E) return;
    int s = src[e]; int v = dst[e]; float wt = w[e];
    const float4 m = *reinterpret_cast<const float4*>(emb + (size_t)s * EMB_D + d);
    float* o = h + (size_t)v * EMB_D + d;
    unsafeAtomicAdd(o + 0, m.x * wt);
    unsafeAtomicAdd(o + 1, m.y * wt);
    unsafeAtomicAdd(o + 2, m.z * wt);
    unsafeAtomicAdd(o + 3, m.w * wt);
}

__global__ void lightgcn_normalize(float* __restrict__ h, int N) {
    int row = blockIdx.x * (blockDim.x >> 6) + (threadIdx.x >> 6);
    int lane = threadIdx.x & 63;
    if (row >= N) return;
    float x = h[(size_t)row * EMB_D + lane];
    float ss = x * x;
    #pragma unroll
    for (int off = 32; off > 0; off >>= 1)
        ss += __shfl_xor(ss, off, 64);
    h[(size_t)row * EMB_D + lane] = x / fmaxf(sqrtf(ss), 1e-12f);
}

extern "C" void kernel_launch(void* const* d_in, const int* in_sizes, int n_in,
                              void* d_out, int out_size, void* d_ws, size_t ws_size,
                              hipStream_t stream) {
    const float* emb = (const float*)d_in[0];   // [N, 64] fp32
    const float* w   = (const float*)d_in[1];   // [E] fp32
    const int*   src = (const int*)d_in[2];     // [E] int32
    const int*   dst = (const int*)d_in[3];     // [E] int32
    float* out = (float*)d_out;

    const int N = in_sizes[0] / EMB_D;
    const int E = in_sizes[1];
    const int block = 256;

    // ---- New tier A workspace: counts[M] | offsets[M+1] | partial | blockoff
    //      | eb4[E] | lv8[E bytes] | pad | emb16  (~19.6 MB) ----
    const int B = (N + NPB - 1) / NPB;          // coarse buckets
    const int M = B * CCH;
    const int numBN = (M + SB - 1) / SB;
    size_t intsN = (size_t)(2 * M + 1 + 2 * numBN) + E;
    size_t lvOff = intsN * sizeof(int);
    size_t embOffN = (lvOff + E + 15) & ~(size_t)15;
    size_t neededN = embOffN + (size_t)N * EMB_D * sizeof(__half);
    bool ldsOK = (size_t)B * sizeof(int) <= 64 * 1024;

    // ---- Tier B (R11) workspace ----
    const int numBA = (N + SB - 1) / SB;
    size_t intsA = (size_t)(9 * N + N + 1 + 2 * numBA) + E;
    size_t embOffA = (intsA * sizeof(int) + 15) & ~(size_t)15;
    size_t neededA = embOffA + (size_t)N * EMB_D * sizeof(__half);

    if (ws_size >= neededN && numBN <= 1024 && ldsOK) {
        int* counts   = (int*)d_ws;              // M
        int* offsets  = counts + M;              // M+1
        int* partial  = offsets + M + 1;
        int* blockoff = partial + numBN;
        unsigned int* eb4 = (unsigned int*)(blockoff + numBN);     // E
        unsigned char* lv8 = (unsigned char*)d_ws + lvOff;         // E bytes
        __half2* emb16 = (__half2*)((char*)d_ws + embOffN);

        const int ppc = (E + CCH - 1) / CCH;
        int n2 = N * (EMB_D / 2);
        size_t shB = (size_t)B * sizeof(int);

        p1_cast_hist<<<CCH + 256, block, shB, stream>>>(
            (const float2*)emb, emb16, n2, dst, counts, E, ppc, B);
        scan_reduceB<<<numBN, SB, 0, stream>>>(counts, partial, M);
        scan_partials<<<1, SB, 0, stream>>>(partial, blockoff, offsets, numBN, M);
        scan_applyB<<<numBN, SB, 0, stream>>>(counts, blockoff, offsets, M);
        p3_scatter<<<CCH, block, shB, stream>>>(src, dst, w, offsets,
                                                eb4, lv8, E, ppc, B);
        p4_gather<<<B, block, 0, stream>>>((const uint2*)emb16, offsets,
                                           eb4, lv8, out, N);
    } else if (ws_size >= neededA && numBA <= 1024) {
        int* counts8  = (int*)d_ws;
        int* cursors  = counts8 + (size_t)8 * N;
        int* offsets  = cursors + N;
        int* partial  = offsets + N + 1;
        int* blockoff = partial + numBA;
        unsigned int* packed = (unsigned int*)(blockoff + numBA);
        __half2* emb16 = (__half2*)((char*)d_ws + embOffA);

        hipMemsetAsync(counts8, 0, (size_t)8 * N * sizeof(int), stream);

        int n2 = N * (EMB_D / 2);
        fused_cast_hist<<<CAST_BLOCKS + 1024, block, 0, stream>>>(
            (const float2*)emb, emb16, n2, dst, counts8, E, N);
        scan_reduceF<<<numBA, SB, 0, stream>>>(counts8, partial, N);
        scan_partials<<<1, SB, 0, stream>>>(partial, blockoff, offsets, numBA, N);
        scan_applyF<<<numBA, SB, 0, stream>>>(counts8, blockoff, offsets, cursors, N);

        int span = (N + 7) / 8;
        bucketS_kernel<<<8 * 256, block, 0, stream>>>(src, dst, w, cursors,
                                                      packed, E, span, N);
        int gridN = (N + 3) / 4;
        gatherS_kernel<<<gridN, 256, 0, stream>>>((const uint2*)emb16, offsets,
                                                  packed, out, N);
    } else {
        hipMemsetAsync(d_out, 0, (size_t)out_size * sizeof(float), stream);
        long long total = (long long)E * 16;
        int grid = (int)((total + block - 1) / block);
        lightgcn_scatter<<<grid, block, 0, stream>>>(emb, w, src, dst, out, E);
        int gridN = (N + 3) / 4;
        lightgcn_normalize<<<gridN, 256, 0, stream>>>(out, N);
    }
}

// Round 13
// 612.881 us; speedup vs baseline: 1.6943x; 1.6943x over previous
//
#include <hip/hip_runtime.h>
#include <hip/hip_fp16.h>

#define EMB_D 64
#define SB 1024   // scan block size
#define NR 8      // node ranges (XCD-affine, == %8 block classes)
#define NS 16     // edge slices

// ===========================================================================
// Tier A: deterministic LDS-cursor counting sort, zero global atomics.
//   P1: 8x16 blocks LDS-hist their (node-range, edge-slice) + fused fp16 cast
//   scan: fold 16 slices -> offsets[v]; rewrite counts16 -> per-slice baselines
//   P3: LDS cursors from baselines -> exact-slot packed scatter
//       (range regions single-XCD -> write-combined)
//   gatherS: per-node segment gather (quarter-wave, 2-deep pipe, fused norm)
// Tier B: R11 pipeline (proven 308 us). Tier C: atomic scatter.
// ===========================================================================

__device__ __forceinline__ float h15_to_float(unsigned int bits) {
    return __half2float(__ushort_as_half((unsigned short)bits));
}

// --- P1: fused cast + per-(range,slice) LDS histogram ---------------------
__global__ void p1_cast_hist(const float2* __restrict__ embin,
                             __half2* __restrict__ emb16, int n2,
                             const int* __restrict__ dst,
                             int* __restrict__ counts16,   // [NS][N]
                             int E, int N, int RS, int ES) {
    extern __shared__ int h[];   // RS ints
    if (blockIdx.x >= NR * NS) {
        int i = (blockIdx.x - NR * NS) * blockDim.x + threadIdx.x;
        int st = (gridDim.x - NR * NS) * blockDim.x;
        for (; i < n2; i += st)
            emb16[i] = __float22half2_rn(embin[i]);
        return;
    }
    const int r = blockIdx.x & 7;
    const int s = blockIdx.x >> 3;
    const int lo = r * RS, hi = min(lo + RS, N), len = hi - lo;
    for (int j = threadIdx.x; j < len; j += blockDim.x) h[j] = 0;
    __syncthreads();
    int elo = s * ES, ehi = min(elo + ES, E);
    for (int i = elo + threadIdx.x; i < ehi; i += blockDim.x) {
        int v = dst[i];
        if (v >= lo && v < hi) atomicAdd(&h[v - lo], 1);
    }
    __syncthreads();
    int* outp = counts16 + (size_t)s * N + lo;
    for (int j = threadIdx.x; j < len; j += blockDim.x) outp[j] = h[j];
}

// --- scan: fold 16 slices -------------------------------------------------
__device__ __forceinline__ int fold16(const int* counts16, int i, int N) {
    int v = 0;
    #pragma unroll
    for (int s = 0; s < NS; ++s) v += counts16[(size_t)s * N + i];
    return v;
}

__global__ void scan_reduce16(const int* __restrict__ counts16,
                              int* __restrict__ partial, int N) {
    __shared__ int wsum[16];
    const int tid = threadIdx.x, lane = tid & 63, wid = tid >> 6;
    int i = blockIdx.x * SB + tid;
    int v = (i < N) ? fold16(counts16, i, N) : 0;
    #pragma unroll
    for (int off = 32; off > 0; off >>= 1)
        v += __shfl_xor(v, off, 64);
    if (lane == 0) wsum[wid] = v;
    __syncthreads();
    if (tid == 0) {
        int s = 0;
        #pragma unroll
        for (int k = 0; k < 16; ++k) s += wsum[k];
        partial[blockIdx.x] = s;
    }
}

__global__ void scan_partials(const int* __restrict__ partial,
                              int* __restrict__ blockoff,
                              int* __restrict__ offsets, int numB, int M) {
    __shared__ int wsum[16];
    __shared__ int wpre[16];
    const int tid = threadIdx.x, lane = tid & 63, wid = tid >> 6;
    int v = (tid < numB) ? partial[tid] : 0;
    int x = v;
    #pragma unroll
    for (int off = 1; off < 64; off <<= 1) {
        int t = __shfl_up(x, off, 64);
        if (lane >= off) x += t;
    }
    if (lane == 63) wsum[wid] = x;
    __syncthreads();
    if (wid == 0) {
        int s = (lane < 16) ? wsum[lane] : 0;
        #pragma unroll
        for (int off = 1; off < 16; off <<= 1) {
            int t = __shfl_up(s, off, 64);
            if (lane >= off) s += t;
        }
        if (lane < 16) wpre[lane] = s;
    }
    __syncthreads();
    int excl = ((wid > 0) ? wpre[wid - 1] : 0) + (x - v);
    if (tid < numB) blockoff[tid] = excl;
    if (tid == 0) offsets[M] = wpre[15];   // grand total = E
}

// offsets[i] = exclusive total; counts16[s][i] rewritten in place to
// per-slice baselines: offsets[i] + sum_{s'<s} counts16[s'][i]
__global__ void scan_apply16(int* __restrict__ counts16,
                             const int* __restrict__ blockoff,
                             int* __restrict__ offsets, int N) {
    __shared__ int wsum[16];
    __shared__ int wpre[16];
    const int tid = threadIdx.x, lane = tid & 63, wid = tid >> 6;
    int i = blockIdx.x * SB + tid;
    int v = (i < N) ? fold16(counts16, i, N) : 0;
    int x = v;
    #pragma unroll
    for (int off = 1; off < 64; off <<= 1) {
        int t = __shfl_up(x, off, 64);
        if (lane >= off) x += t;
    }
    if (lane == 63) wsum[wid] = x;
    __syncthreads();
    if (wid == 0) {
        int s = (lane < 16) ? wsum[lane] : 0;
        #pragma unroll
        for (int off = 1; off < 16; off <<= 1) {
            int t = __shfl_up(s, off, 64);
            if (lane >= off) s += t;
        }
        if (lane < 16) wpre[lane] = s;
    }
    __syncthreads();
    int excl = blockoff[blockIdx.x] + ((wid > 0) ? wpre[wid - 1] : 0) + (x - v);
    if (i < N) {
        offsets[i] = excl;
        int base = excl;
        #pragma unroll
        for (int s = 0; s < NS; ++s) {
            int c = counts16[(size_t)s * N + i];
            counts16[(size_t)s * N + i] = base;
            base += c;
        }
    }
}

// --- P3: exact-slot scatter via LDS cursors (zero global atomics) ---------
// Block (r,s): cursors = baselines for its node range; range r's CSR region
// is written ONLY by blockIdx&7==r (one XCD) -> write-combined stores.
__global__ void p3_scatter(const int* __restrict__ src,
                           const int* __restrict__ dst,
                           const float* __restrict__ w,
                           const int* __restrict__ cumul16,  // [NS][N]
                           unsigned int* __restrict__ packed,
                           int E, int N, int RS, int ES) {
    extern __shared__ int cur[];   // RS ints
    const int r = blockIdx.x & 7;
    const int s = blockIdx.x >> 3;
    const int lo = r * RS, hi = min(lo + RS, N), len = hi - lo;
    const int* basep = cumul16 + (size_t)s * N + lo;
    for (int j = threadIdx.x; j < len; j += blockDim.x) cur[j] = basep[j];
    __syncthreads();
    int elo = s * ES, ehi = min(elo + ES, E);
    for (int i = elo + threadIdx.x; i < ehi; i += blockDim.x) {
        int v = dst[i];
        if (v >= lo && v < hi) {
            int slot = atomicAdd(&cur[v - lo], 1);   // LDS atomic
            unsigned int wb = __half_as_ushort(__float2half_rn(w[i]));
            packed[slot] = ((unsigned int)src[i] << 15) | (wb & 0x7FFFu);
        }
    }
}

// --- gatherS: fp16 gather, quarter-wave per edge, 2-deep pipeline ---------
__global__ __launch_bounds__(256) void gatherS_kernel(
        const uint2* __restrict__ emb16,       // row v = 16 x uint2 (128 B)
        const int* __restrict__ offsets,       // [N+1]
        const unsigned int* __restrict__ packed,
        float* __restrict__ out, int N) {
    int node = blockIdx.x * 4 + (threadIdx.x >> 6);
    int lane = threadIdx.x & 63;
    if (node >= N) return;
    int q  = lane >> 4;
    int ql = lane & 15;

    int beg = offsets[node];
    int end = offsets[node + 1];

    float a0 = 0.f, a1 = 0.f, a2 = 0.f, a3 = 0.f;

    int idx0 = beg + q;
    unsigned int pk0 = (idx0 < end) ? packed[idx0] : 0u;
    uint2 r0 = emb16[(size_t)(pk0 >> 15) * 16 + ql];

    for (int j = beg; j < end; j += 4) {
        int idx1 = idx0 + 4;
        unsigned int pk1 = (idx1 < end) ? packed[idx1] : 0u;
        uint2 r1 = emb16[(size_t)(pk1 >> 15) * 16 + ql];  // next in flight

        float wt = h15_to_float(pk0 & 0x7FFFu);
        float2 x01 = __half22float2(*reinterpret_cast<__half2*>(&r0.x));
        float2 x23 = __half22float2(*reinterpret_cast<__half2*>(&r0.y));
        a0 = fmaf(x01.x, wt, a0);
        a1 = fmaf(x01.y, wt, a1);
        a2 = fmaf(x23.x, wt, a2);
        a3 = fmaf(x23.y, wt, a3);

        pk0 = pk1; r0 = r1; idx0 = idx1;
    }

    a0 += __shfl_xor(a0, 16, 64); a0 += __shfl_xor(a0, 32, 64);
    a1 += __shfl_xor(a1, 16, 64); a1 += __shfl_xor(a1, 32, 64);
    a2 += __shfl_xor(a2, 16, 64); a2 += __shfl_xor(a2, 32, 64);
    a3 += __shfl_xor(a3, 16, 64); a3 += __shfl_xor(a3, 32, 64);

    float ss = a0 * a0 + a1 * a1 + a2 * a2 + a3 * a3;
    #pragma unroll
    for (int off = 8; off > 0; off >>= 1)
        ss += __shfl_xor(ss, off, 64);
    float scale = 1.0f / fmaxf(sqrtf(ss), 1e-12f);

    if (q == 0) {
        float4 o = make_float4(a0 * scale, a1 * scale, a2 * scale, a3 * scale);
        reinterpret_cast<float4*>(out + (size_t)node * EMB_D)[ql] = o;
    }
}

// ===========================================================================
// Tier B: R11 pipeline (proven 308 us).
// ===========================================================================
#define CAST_BLOCKS 256
__global__ void fused_cast_hist(const float2* __restrict__ embin,
                                __half2* __restrict__ emb16, int n2,
                                const int* __restrict__ dst,
                                int* __restrict__ counts8, int E, int N) {
    if (blockIdx.x < CAST_BLOCKS) {
        int i = blockIdx.x * blockDim.x + threadIdx.x;
        int st = CAST_BLOCKS * blockDim.x;
        for (; i < n2; i += st)
            emb16[i] = __float22half2_rn(embin[i]);
    } else {
        int* mycounts = counts8 + (size_t)(blockIdx.x & 7) * N;
        int i = (blockIdx.x - CAST_BLOCKS) * blockDim.x + threadIdx.x;
        int st = (gridDim.x - CAST_BLOCKS) * blockDim.x;
        for (; i < E; i += st)
            atomicAdd(&mycounts[dst[i]], 1);
    }
}

__device__ __forceinline__ int fold8(const int* counts8, int i, int N) {
    int v = 0;
    #pragma unroll
    for (int g = 0; g < 8; ++g) v += counts8[(size_t)g * N + i];
    return v;
}

__global__ void scan_reduceF(const int* __restrict__ counts8,
                             int* __restrict__ partial, int N) {
    __shared__ int wsum[16];
    const int tid = threadIdx.x, lane = tid & 63, wid = tid >> 6;
    int i = blockIdx.x * SB + tid;
    int v = (i < N) ? fold8(counts8, i, N) : 0;
    #pragma unroll
    for (int off = 32; off > 0; off >>= 1)
        v += __shfl_xor(v, off, 64);
    if (lane == 0) wsum[wid] = v;
    __syncthreads();
    if (tid == 0) {
        int s = 0;
        #pragma unroll
        for (int k = 0; k < 16; ++k) s += wsum[k];
        partial[blockIdx.x] = s;
    }
}

__global__ void scan_applyF(const int* __restrict__ counts8,
                            const int* __restrict__ blockoff,
                            int* __restrict__ offsets,
                            int* __restrict__ cursors, int N) {
    __shared__ int wsum[16];
    __shared__ int wpre[16];
    const int tid = threadIdx.x, lane = tid & 63, wid = tid >> 6;
    int i = blockIdx.x * SB + tid;
    int v = (i < N) ? fold8(counts8, i, N) : 0;
    int x = v;
    #pragma unroll
    for (int off = 1; off < 64; off <<= 1) {
        int t = __shfl_up(x, off, 64);
        if (lane >= off) x += t;
    }
    if (lane == 63) wsum[wid] = x;
    __syncthreads();
    if (wid == 0) {
        int s = (lane < 16) ? wsum[lane] : 0;
        #pragma unroll
        for (int off = 1; off < 16; off <<= 1) {
            int t = __shfl_up(s, off, 64);
            if (lane >= off) s += t;
        }
        if (lane < 16) wpre[lane] = s;
    }
    __syncthreads();
    int excl = blockoff[blockIdx.x] + ((wid > 0) ? wpre[wid - 1] : 0) + (x - v);
    if (i < N) { offsets[i] = excl; cursors[i] = excl; }
}

__global__ void bucketS_kernel(const int* __restrict__ src,
                               const int* __restrict__ dst,
                               const float* __restrict__ w,
                               int* __restrict__ cursors,
                               unsigned int* __restrict__ packed,
                               int E, int span, int N) {
    int g = blockIdx.x & 7;
    int b = blockIdx.x >> 3;
    int lo = g * span;
    int hi = min(lo + span, N);
    int stride = (gridDim.x >> 3) * blockDim.x;
    for (int i = b * blockDim.x + threadIdx.x; i < E; i += stride) {
        int v = dst[i];
        if (v >= lo && v < hi) {
            int slot = atomicAdd(&cursors[v], 1);
            unsigned int wb = __half_as_ushort(__float2half_rn(w[i]));
            packed[slot] = ((unsigned int)src[i] << 15) | (wb & 0x7FFFu);
        }
    }
}

// ===========================================================================
// Tier C: atomic scatter fallback.
// ===========================================================================
__global__ void lightgcn_scatter(const float* __restrict__ emb,
                                 const float* __restrict__ w,
                                 const int* __restrict__ src,
                                 const int* __restrict__ dst,
                                 float* __restrict__ h, int E) {
    long long t = (long long)blockIdx.x * blockDim.x + threadIdx.x;
    int e = (int)(t >> 4);
    int d = (int)(t & 15) << 2;
    if (e >= E) return;
    int s = src[e]; int v = dst[e]; float wt = w[e];
    const float4 m = *reinterpret_cast<const float4*>(emb + (size_t)s * EMB_D + d);
    float* o = h + (size_t)v * EMB_D + d;
    unsafeAtomicAdd(o + 0, m.x * wt);
    unsafeAtomicAdd(o + 1, m.y * wt);
    unsafeAtomicAdd(o + 2, m.z * wt);
    unsafeAtomicAdd(o + 3, m.w * wt);
}

__global__ void lightgcn_normalize(float* __restrict__ h, int N) {
    int row = blockIdx.x * (blockDim.x >> 6) + (threadIdx.x >> 6);
    int lane = threadIdx.x & 63;
    if (row >= N) return;
    float x = h[(size_t)row * EMB_D + lane];
    float ss = x * x;
    #pragma unroll
    for (int off = 32; off > 0; off >>= 1)
        ss += __shfl_xor(ss, off, 64);
    h[(size_t)row * EMB_D + lane] = x / fmaxf(sqrtf(ss), 1e-12f);
}

extern "C" void kernel_launch(void* const* d_in, const int* in_sizes, int n_in,
                              void* d_out, int out_size, void* d_ws, size_t ws_size,
                              hipStream_t stream) {
    const float* emb = (const float*)d_in[0];   // [N, 64] fp32
    const float* w   = (const float*)d_in[1];   // [E] fp32
    const int*   src = (const int*)d_in[2];     // [E] int32
    const int*   dst = (const int*)d_in[3];     // [E] int32
    float* out = (float*)d_out;

    const int N = in_sizes[0] / EMB_D;
    const int E = in_sizes[1];
    const int block = 256;
    const int numB = (N + SB - 1) / SB;

    // ---- Tier A workspace: counts16[16N] | offsets[N+1] | partial | blockoff
    //      | packed[E] | pad | emb16  (~22 MB) ----
    const int RS = (N + NR - 1) / NR;
    const int ES = (E + NS - 1) / NS;
    size_t intsN = (size_t)NS * N + (N + 1) + 2 * numB + E;
    size_t embOffN = (intsN * sizeof(int) + 15) & ~(size_t)15;
    size_t neededN = embOffN + (size_t)N * EMB_D * sizeof(__half);
    size_t shLDS = (size_t)RS * sizeof(int);
    bool ldsOK = shLDS <= 64 * 1024;

    // ---- Tier B (R11) workspace ----
    size_t intsA = (size_t)(9 * N + N + 1 + 2 * numB) + E;
    size_t embOffA = (intsA * sizeof(int) + 15) & ~(size_t)15;
    size_t neededA = embOffA + (size_t)N * EMB_D * sizeof(__half);

    if (ws_size >= neededN && numB <= 1024 && ldsOK) {
        int* counts16 = (int*)d_ws;              // NS*N (-> baselines)
        int* offsets  = counts16 + (size_t)NS * N;  // N+1
        int* partial  = offsets + N + 1;
        int* blockoff = partial + numB;
        unsigned int* packed = (unsigned int*)(blockoff + numB);   // E
        __half2* emb16 = (__half2*)((char*)d_ws + embOffN);

        int n2 = N * (EMB_D / 2);
        p1_cast_hist<<<NR * NS + 256, block, shLDS, stream>>>(
            (const float2*)emb, emb16, n2, dst, counts16, E, N, RS, ES);
        scan_reduce16<<<numB, SB, 0, stream>>>(counts16, partial, N);
        scan_partials<<<1, SB, 0, stream>>>(partial, blockoff, offsets, numB, N);
        scan_apply16<<<numB, SB, 0, stream>>>(counts16, blockoff, offsets, N);
        p3_scatter<<<NR * NS, block, shLDS, stream>>>(src, dst, w, counts16,
                                                      packed, E, N, RS, ES);
        int gridN = (N + 3) / 4;
        gatherS_kernel<<<gridN, 256, 0, stream>>>((const uint2*)emb16, offsets,
                                                  packed, out, N);
    } else if (ws_size >= neededA && numB <= 1024) {
        int* counts8  = (int*)d_ws;
        int* cursors  = counts8 + (size_t)8 * N;
        int* offsets  = cursors + N;
        int* partial  = offsets + N + 1;
        int* blockoff = partial + numB;
        unsigned int* packed = (unsigned int*)(blockoff + numB);
        __half2* emb16 = (__half2*)((char*)d_ws + embOffA);

        hipMemsetAsync(counts8, 0, (size_t)8 * N * sizeof(int), stream);

        int n2 = N * (EMB_D / 2);
        fused_cast_hist<<<CAST_BLOCKS + 1024, block, 0, stream>>>(
            (const float2*)emb, emb16, n2, dst, counts8, E, N);
        scan_reduceF<<<numB, SB, 0, stream>>>(counts8, partial, N);
        scan_partials<<<1, SB, 0, stream>>>(partial, blockoff, offsets, numB, N);
        scan_applyF<<<numB, SB, 0, stream>>>(counts8, blockoff, offsets, cursors, N);

        int span = (N + 7) / 8;
        bucketS_kernel<<<8 * 256, block, 0, stream>>>(src, dst, w, cursors,
                                                      packed, E, span, N);
        int gridN = (N + 3) / 4;
        gatherS_kernel<<<gridN, 256, 0, stream>>>((const uint2*)emb16, offsets,
                                                  packed, out, N);
    } else {
        hipMemsetAsync(d_out, 0, (size_t)out_size * sizeof(float), stream);
        long long total = (long long)E * 16;
        int grid = (int)((total + block - 1) / block);
        lightgcn_scatter<<<grid, block, 0, stream>>>(emb, w, src, dst, out, E);
        int gridN = (N + 3) / 4;
        lightgcn_normalize<<<gridN, 256, 0, stream>>>(out, N);
    }
}

// Round 14
// 268.442 us; speedup vs baseline: 3.8682x; 2.2831x over previous
//
#include <hip/hip_runtime.h>
#include <hip/hip_fp16.h>

#define EMB_D 64
#define SB 1024   // scan block size

// ===========================================================================
// Tier A: ONE global-atomic pass total.
//   P1: fused fp16 cast + hist capturing ranks from atomic return (ushort)
//   scan: 3-phase -> offsets
//   P2: atomic-free bucket: packed[offsets[v]+ranks[i]] = (src17|w15),
//       8 node-span groups, single-XCD region ownership (write-combined)
//   P3: gatherS (quarter-wave, 2-deep pipeline, fused L2 norm)
// Tier B: R11 pipeline (proven 308 us). Tier C: atomic scatter.
// ===========================================================================

__device__ __forceinline__ float h15_to_float(unsigned int bits) {
    return __half2float(__ushort_as_half((unsigned short)bits));
}

// --- P1: fused cast + histogram-with-ranks --------------------------------
#define CAST_BLOCKS 256
__global__ void p1_cast_hist_ranks(const float2* __restrict__ embin,
                                   __half2* __restrict__ emb16, int n2,
                                   const int* __restrict__ dst,
                                   int* __restrict__ counts,
                                   unsigned short* __restrict__ ranks,
                                   int E) {
    if (blockIdx.x < CAST_BLOCKS) {
        int i = blockIdx.x * blockDim.x + threadIdx.x;
        int st = CAST_BLOCKS * blockDim.x;
        for (; i < n2; i += st)
            emb16[i] = __float22half2_rn(embin[i]);
    } else {
        int i = (blockIdx.x - CAST_BLOCKS) * blockDim.x + threadIdx.x;
        int st = (gridDim.x - CAST_BLOCKS) * blockDim.x;
        for (; i < E; i += st)
            ranks[i] = (unsigned short)atomicAdd(&counts[dst[i]], 1);
    }
}

// --- generic 3-phase exclusive scan ---------------------------------------
__global__ void scan_reduceB(const int* __restrict__ counts,
                             int* __restrict__ partial, int M) {
    __shared__ int wsum[16];
    const int tid = threadIdx.x, lane = tid & 63, wid = tid >> 6;
    int i = blockIdx.x * SB + tid;
    int v = (i < M) ? counts[i] : 0;
    #pragma unroll
    for (int off = 32; off > 0; off >>= 1)
        v += __shfl_xor(v, off, 64);
    if (lane == 0) wsum[wid] = v;
    __syncthreads();
    if (tid == 0) {
        int s = 0;
        #pragma unroll
        for (int k = 0; k < 16; ++k) s += wsum[k];
        partial[blockIdx.x] = s;
    }
}

__global__ void scan_partials(const int* __restrict__ partial,
                              int* __restrict__ blockoff,
                              int* __restrict__ offsets, int numB, int M) {
    __shared__ int wsum[16];
    __shared__ int wpre[16];
    const int tid = threadIdx.x, lane = tid & 63, wid = tid >> 6;
    int v = (tid < numB) ? partial[tid] : 0;
    int x = v;
    #pragma unroll
    for (int off = 1; off < 64; off <<= 1) {
        int t = __shfl_up(x, off, 64);
        if (lane >= off) x += t;
    }
    if (lane == 63) wsum[wid] = x;
    __syncthreads();
    if (wid == 0) {
        int s = (lane < 16) ? wsum[lane] : 0;
        #pragma unroll
        for (int off = 1; off < 16; off <<= 1) {
            int t = __shfl_up(s, off, 64);
            if (lane >= off) s += t;
        }
        if (lane < 16) wpre[lane] = s;
    }
    __syncthreads();
    int excl = ((wid > 0) ? wpre[wid - 1] : 0) + (x - v);
    if (tid < numB) blockoff[tid] = excl;
    if (tid == 0) offsets[M] = wpre[15];   // grand total = E
}

__global__ void scan_applyB(const int* __restrict__ counts,
                            const int* __restrict__ blockoff,
                            int* __restrict__ offsets, int M) {
    __shared__ int wsum[16];
    __shared__ int wpre[16];
    const int tid = threadIdx.x, lane = tid & 63, wid = tid >> 6;
    int i = blockIdx.x * SB + tid;
    int v = (i < M) ? counts[i] : 0;
    int x = v;
    #pragma unroll
    for (int off = 1; off < 64; off <<= 1) {
        int t = __shfl_up(x, off, 64);
        if (lane >= off) x += t;
    }
    if (lane == 63) wsum[wid] = x;
    __syncthreads();
    if (wid == 0) {
        int s = (lane < 16) ? wsum[lane] : 0;
        #pragma unroll
        for (int off = 1; off < 16; off <<= 1) {
            int t = __shfl_up(s, off, 64);
            if (lane >= off) s += t;
        }
        if (lane < 16) wpre[lane] = s;
    }
    __syncthreads();
    int excl = blockoff[blockIdx.x] + ((wid > 0) ? wpre[wid - 1] : 0) + (x - v);
    if (i < M) offsets[i] = excl;
}

// --- P2: atomic-free packed bucket, 8 node-span groups, 1-XCD regions -----
// Group g = blockIdx&7 owns node span [g*span,(g+1)*span): its CSR region is
// written ONLY by blocks with blockIdx%8==g (one XCD under round-robin
// dispatch) -> full-line write combining. Slot is exact: offsets[v]+ranks[i].
__global__ void bucketR_kernel(const int* __restrict__ src,
                               const int* __restrict__ dst,
                               const float* __restrict__ w,
                               const unsigned short* __restrict__ ranks,
                               const int* __restrict__ offsets,
                               unsigned int* __restrict__ packed,
                               int E, int span, int N) {
    int g = blockIdx.x & 7;
    int b = blockIdx.x >> 3;
    int lo = g * span;
    int hi = min(lo + span, N);
    int stride = (gridDim.x >> 3) * blockDim.x;
    for (int i = b * blockDim.x + threadIdx.x; i < E; i += stride) {
        int v = dst[i];
        if (v >= lo && v < hi) {
            unsigned int wb = __half_as_ushort(__float2half_rn(w[i]));
            packed[offsets[v] + (int)ranks[i]] =
                ((unsigned int)src[i] << 15) | (wb & 0x7FFFu);
        }
    }
}

// --- P3: fp16 gather, quarter-wave per edge, 2-deep pipeline --------------
__global__ __launch_bounds__(256) void gatherS_kernel(
        const uint2* __restrict__ emb16,       // row v = 16 x uint2 (128 B)
        const int* __restrict__ offsets,       // [N+1]
        const unsigned int* __restrict__ packed,
        float* __restrict__ out, int N) {
    int node = blockIdx.x * 4 + (threadIdx.x >> 6);
    int lane = threadIdx.x & 63;
    if (node >= N) return;
    int q  = lane >> 4;
    int ql = lane & 15;

    int beg = offsets[node];
    int end = offsets[node + 1];

    float a0 = 0.f, a1 = 0.f, a2 = 0.f, a3 = 0.f;

    int idx0 = beg + q;
    unsigned int pk0 = (idx0 < end) ? packed[idx0] : 0u;
    uint2 r0 = emb16[(size_t)(pk0 >> 15) * 16 + ql];

    for (int j = beg; j < end; j += 4) {
        int idx1 = idx0 + 4;
        unsigned int pk1 = (idx1 < end) ? packed[idx1] : 0u;
        uint2 r1 = emb16[(size_t)(pk1 >> 15) * 16 + ql];  // next in flight

        float wt = h15_to_float(pk0 & 0x7FFFu);
        float2 x01 = __half22float2(*reinterpret_cast<__half2*>(&r0.x));
        float2 x23 = __half22float2(*reinterpret_cast<__half2*>(&r0.y));
        a0 = fmaf(x01.x, wt, a0);
        a1 = fmaf(x01.y, wt, a1);
        a2 = fmaf(x23.x, wt, a2);
        a3 = fmaf(x23.y, wt, a3);

        pk0 = pk1; r0 = r1; idx0 = idx1;
    }

    a0 += __shfl_xor(a0, 16, 64); a0 += __shfl_xor(a0, 32, 64);
    a1 += __shfl_xor(a1, 16, 64); a1 += __shfl_xor(a1, 32, 64);
    a2 += __shfl_xor(a2, 16, 64); a2 += __shfl_xor(a2, 32, 64);
    a3 += __shfl_xor(a3, 16, 64); a3 += __shfl_xor(a3, 32, 64);

    float ss = a0 * a0 + a1 * a1 + a2 * a2 + a3 * a3;
    #pragma unroll
    for (int off = 8; off > 0; off >>= 1)
        ss += __shfl_xor(ss, off, 64);
    float scale = 1.0f / fmaxf(sqrtf(ss), 1e-12f);

    if (q == 0) {
        float4 o = make_float4(a0 * scale, a1 * scale, a2 * scale, a3 * scale);
        reinterpret_cast<float4*>(out + (size_t)node * EMB_D)[ql] = o;
    }
}

// ===========================================================================
// Tier B: R11 pipeline (proven 308 us).
// ===========================================================================
__global__ void fused_cast_hist(const float2* __restrict__ embin,
                                __half2* __restrict__ emb16, int n2,
                                const int* __restrict__ dst,
                                int* __restrict__ counts8, int E, int N) {
    if (blockIdx.x < CAST_BLOCKS) {
        int i = blockIdx.x * blockDim.x + threadIdx.x;
        int st = CAST_BLOCKS * blockDim.x;
        for (; i < n2; i += st)
            emb16[i] = __float22half2_rn(embin[i]);
    } else {
        int* mycounts = counts8 + (size_t)(blockIdx.x & 7) * N;
        int i = (blockIdx.x - CAST_BLOCKS) * blockDim.x + threadIdx.x;
        int st = (gridDim.x - CAST_BLOCKS) * blockDim.x;
        for (; i < E; i += st)
            atomicAdd(&mycounts[dst[i]], 1);
    }
}

__device__ __forceinline__ int fold8(const int* counts8, int i, int N) {
    int v = 0;
    #pragma unroll
    for (int g = 0; g < 8; ++g) v += counts8[(size_t)g * N + i];
    return v;
}

__global__ void scan_reduceF(const int* __restrict__ counts8,
                             int* __restrict__ partial, int N) {
    __shared__ int wsum[16];
    const int tid = threadIdx.x, lane = tid & 63, wid = tid >> 6;
    int i = blockIdx.x * SB + tid;
    int v = (i < N) ? fold8(counts8, i, N) : 0;
    #pragma unroll
    for (int off = 32; off > 0; off >>= 1)
        v += __shfl_xor(v, off, 64);
    if (lane == 0) wsum[wid] = v;
    __syncthreads();
    if (tid == 0) {
        int s = 0;
        #pragma unroll
        for (int k = 0; k < 16; ++k) s += wsum[k];
        partial[blockIdx.x] = s;
    }
}

__global__ void scan_applyF(const int* __restrict__ counts8,
                            const int* __restrict__ blockoff,
                            int* __restrict__ offsets,
                            int* __restrict__ cursors, int N) {
    __shared__ int wsum[16];
    __shared__ int wpre[16];
    const int tid = threadIdx.x, lane = tid & 63, wid = tid >> 6;
    int i = blockIdx.x * SB + tid;
    int v = (i < N) ? fold8(counts8, i, N) : 0;
    int x = v;
    #pragma unroll
    for (int off = 1; off < 64; off <<= 1) {
        int t = __shfl_up(x, off, 64);
        if (lane >= off) x += t;
    }
    if (lane == 63) wsum[wid] = x;
    __syncthreads();
    if (wid == 0) {
        int s = (lane < 16) ? wsum[lane] : 0;
        #pragma unroll
        for (int off = 1; off < 16; off <<= 1) {
            int t = __shfl_up(s, off, 64);
            if (lane >= off) s += t;
        }
        if (lane < 16) wpre[lane] = s;
    }
    __syncthreads();
    int excl = blockoff[blockIdx.x] + ((wid > 0) ? wpre[wid - 1] : 0) + (x - v);
    if (i < N) { offsets[i] = excl; cursors[i] = excl; }
}

__global__ void bucketS_kernel(const int* __restrict__ src,
                               const int* __restrict__ dst,
                               const float* __restrict__ w,
                               int* __restrict__ cursors,
                               unsigned int* __restrict__ packed,
                               int E, int span, int N) {
    int g = blockIdx.x & 7;
    int b = blockIdx.x >> 3;
    int lo = g * span;
    int hi = min(lo + span, N);
    int stride = (gridDim.x >> 3) * blockDim.x;
    for (int i = b * blockDim.x + threadIdx.x; i < E; i += stride) {
        int v = dst[i];
        if (v >= lo && v < hi) {
            int slot = atomicAdd(&cursors[v], 1);
            unsigned int wb = __half_as_ushort(__float2half_rn(w[i]));
            packed[slot] = ((unsigned int)src[i] << 15) | (wb & 0x7FFFu);
        }
    }
}

// ===========================================================================
// Tier C: atomic scatter fallback.
// ===========================================================================
__global__ void lightgcn_scatter(const float* __restrict__ emb,
                                 const float* __restrict__ w,
                                 const int* __restrict__ src,
                                 const int* __restrict__ dst,
                                 float* __restrict__ h, int E) {
    long long t = (long long)blockIdx.x * blockDim.x + threadIdx.x;
    int e = (int)(t >> 4);
    int d = (int)(t & 15) << 2;
    if (e >= E) return;
    int s = src[e]; int v = dst[e]; float wt = w[e];
    const float4 m = *reinterpret_cast<const float4*>(emb + (size_t)s * EMB_D + d);
    float* o = h + (size_t)v * EMB_D + d;
    unsafeAtomicAdd(o + 0, m.x * wt);
    unsafeAtomicAdd(o + 1, m.y * wt);
    unsafeAtomicAdd(o + 2, m.z * wt);
    unsafeAtomicAdd(o + 3, m.w * wt);
}

__global__ void lightgcn_normalize(float* __restrict__ h, int N) {
    int row = blockIdx.x * (blockDim.x >> 6) + (threadIdx.x >> 6);
    int lane = threadIdx.x & 63;
    if (row >= N) return;
    float x = h[(size_t)row * EMB_D + lane];
    float ss = x * x;
    #pragma unroll
    for (int off = 32; off > 0; off >>= 1)
        ss += __shfl_xor(ss, off, 64);
    h[(size_t)row * EMB_D + lane] = x / fmaxf(sqrtf(ss), 1e-12f);
}

extern "C" void kernel_launch(void* const* d_in, const int* in_sizes, int n_in,
                              void* d_out, int out_size, void* d_ws, size_t ws_size,
                              hipStream_t stream) {
    const float* emb = (const float*)d_in[0];   // [N, 64] fp32
    const float* w   = (const float*)d_in[1];   // [E] fp32
    const int*   src = (const int*)d_in[2];     // [E] int32
    const int*   dst = (const int*)d_in[3];     // [E] int32
    float* out = (float*)d_out;

    const int N = in_sizes[0] / EMB_D;
    const int E = in_sizes[1];
    const int block = 256;
    const int numB = (N + SB - 1) / SB;

    // ---- Tier A workspace: counts[N] | offsets[N+1] | partial | blockoff |
    //      packed[E] | ranks ushort[E] | pad | emb16  (~21.7 MB) ----
    size_t intsA = (size_t)(2 * N + 1 + 2 * numB) + E;
    size_t ranksOff = intsA * sizeof(int);
    size_t embOffA = (ranksOff + (size_t)E * sizeof(unsigned short) + 15)
                     & ~(size_t)15;
    size_t neededA = embOffA + (size_t)N * EMB_D * sizeof(__half);

    // ---- Tier B (R11) workspace ----
    size_t intsB = (size_t)(9 * N + N + 1 + 2 * numB) + E;
    size_t embOffB = (intsB * sizeof(int) + 15) & ~(size_t)15;
    size_t neededB = embOffB + (size_t)N * EMB_D * sizeof(__half);

    if (ws_size >= neededA && numB <= 1024) {
        int* counts   = (int*)d_ws;              // N
        int* offsets  = counts + N;              // N+1
        int* partial  = offsets + N + 1;
        int* blockoff = partial + numB;
        unsigned int* packed = (unsigned int*)(blockoff + numB);   // E
        unsigned short* ranks = (unsigned short*)((char*)d_ws + ranksOff);
        __half2* emb16 = (__half2*)((char*)d_ws + embOffA);

        hipMemsetAsync(counts, 0, (size_t)N * sizeof(int), stream);

        int n2 = N * (EMB_D / 2);
        p1_cast_hist_ranks<<<CAST_BLOCKS + 1024, block, 0, stream>>>(
            (const float2*)emb, emb16, n2, dst, counts, ranks, E);

        scan_reduceB<<<numB, SB, 0, stream>>>(counts, partial, N);
        scan_partials<<<1, SB, 0, stream>>>(partial, blockoff, offsets, numB, N);
        scan_applyB<<<numB, SB, 0, stream>>>(counts, blockoff, offsets, N);

        int span = (N + 7) / 8;
        bucketR_kernel<<<8 * 256, block, 0, stream>>>(src, dst, w, ranks,
                                                      offsets, packed, E, span, N);

        int gridN = (N + 3) / 4;
        gatherS_kernel<<<gridN, 256, 0, stream>>>((const uint2*)emb16, offsets,
                                                  packed, out, N);
    } else if (ws_size >= neededB && numB <= 1024) {
        int* counts8  = (int*)d_ws;
        int* cursors  = counts8 + (size_t)8 * N;
        int* offsets  = cursors + N;
        int* partial  = offsets + N + 1;
        int* blockoff = partial + numB;
        unsigned int* packed = (unsigned int*)(blockoff + numB);
        __half2* emb16 = (__half2*)((char*)d_ws + embOffB);

        hipMemsetAsync(counts8, 0, (size_t)8 * N * sizeof(int), stream);

        int n2 = N * (EMB_D / 2);
        fused_cast_hist<<<CAST_BLOCKS + 1024, block, 0, stream>>>(
            (const float2*)emb, emb16, n2, dst, counts8, E, N);
        scan_reduceF<<<numB, SB, 0, stream>>>(counts8, partial, N);
        scan_partials<<<1, SB, 0, stream>>>(partial, blockoff, offsets, numB, N);
        scan_applyF<<<numB, SB, 0, stream>>>(counts8, blockoff, offsets, cursors, N);

        int span = (N + 7) / 8;
        bucketS_kernel<<<8 * 256, block, 0, stream>>>(src, dst, w, cursors,
                                                      packed, E, span, N);
        int gridN = (N + 3) / 4;
        gatherS_kernel<<<gridN, 256, 0, stream>>>((const uint2*)emb16, offsets,
                                                  packed, out, N);
    } else {
        hipMemsetAsync(d_out, 0, (size_t)out_size * sizeof(float), stream);
        long long total = (long long)E * 16;
        int grid = (int)((total + block - 1) / block);
        lightgcn_scatter<<<grid, block, 0, stream>>>(emb, w, src, dst, out, E);
        int gridN = (N + 3) / 4;
        lightgcn_normalize<<<gridN, 256, 0, stream>>>(out, N);
    }
}